// Round 16
// baseline (274.829 us; speedup 1.0000x reference)
//
#include <hip/hip_runtime.h>

typedef __attribute__((ext_vector_type(8))) short short8;
typedef __attribute__((ext_vector_type(4))) float f32x4;

#define DIMD 512
#define EE 1024
#define SSS 128
#define LLL 4096
#define NROW 16384   // B*L
#define NUV 2176     // 2E+S

__device__ __forceinline__ short f2bf(float f) {
  union { float f; unsigned u; } un; un.f = f;
  unsigned r = un.u + 0x7FFFu + ((un.u >> 16) & 1u);
  return (short)(r >> 16);
}
__device__ __forceinline__ float bf2f(short s) {
  union { unsigned u; float f; } un;
  un.u = ((unsigned)(unsigned short)s) << 16;
  return un.f;
}
__device__ __forceinline__ float silu_f(float x) {
  return x / (1.0f + __expf(-x));
}

__device__ __forceinline__ void gld16(const short* g, short* l) {
  __builtin_amdgcn_global_load_lds(
      (const __attribute__((address_space(1))) unsigned int*)g,
      (__attribute__((address_space(3))) unsigned int*)l, 16, 0, 0);
}

#define MFMA16(a, b, c) c = __builtin_amdgcn_mfma_f32_16x16x32_bf16(a, b, c, 0, 0, 0)
#define SBAR() asm volatile("s_barrier" ::: "memory")
#define VMCNT(n) asm volatile("s_waitcnt vmcnt(" #n ")" ::: "memory")

// ---------------- fused prep+layernorm ----------------
__global__ __launch_bounds__(256) void prepln_kernel(
    const float* __restrict__ x, const float* __restrict__ w, const float* __restrict__ bb,
    short* __restrict__ xn,
    const float* __restrict__ W_uv, const float* __restrict__ W_out,
    short* __restrict__ W_uvT, short* __restrict__ W_outT) {
  int tid = threadIdx.x;
  int bx = blockIdx.x;
  if (bx >= NROW) {
    __shared__ float tile[64][65];
    int wb = bx - NROW;
    const float* src; short* dst; int s0, c0, ldS, ldD;
    if (wb < 272) {
      int dt = wb / 34, ct = wb - dt * 34;
      s0 = dt * 64; c0 = ct * 64; ldS = NUV; ldD = DIMD;
      src = W_uv; dst = W_uvT;
    } else {
      int wb2 = wb - 272;
      int et = wb2 >> 3, dt = wb2 & 7;
      s0 = et * 64; c0 = dt * 64; ldS = DIMD; ldD = EE;
      src = W_out; dst = W_outT;
    }
    int r0 = tid >> 6, c = tid & 63;
    #pragma unroll
    for (int rr = 0; rr < 16; ++rr) {
      int row = rr * 4 + r0;
      tile[row][c] = src[(size_t)(s0 + row) * ldS + c0 + c];
    }
    __syncthreads();
    #pragma unroll
    for (int rr = 0; rr < 16; ++rr) {
      int row = rr * 4 + r0;
      dst[(size_t)(c0 + row) * ldD + s0 + c] = f2bf(tile[c][row]);
    }
    return;
  }
  int row = bx;
  const float2* xr = (const float2*)(x + (size_t)row * DIMD);
  float2 v = xr[tid];
  float s = v.x + v.y, ss = v.x * v.x + v.y * v.y;
  #pragma unroll
  for (int off = 32; off >= 1; off >>= 1) {
    s += __shfl_down(s, off);
    ss += __shfl_down(ss, off);
  }
  __shared__ float ps[8];
  if ((tid & 63) == 0) { ps[tid >> 6] = s; ps[4 + (tid >> 6)] = ss; }
  __syncthreads();
  s = ps[0] + ps[1] + ps[2] + ps[3];
  ss = ps[4] + ps[5] + ps[6] + ps[7];
  float mu = s * (1.0f / DIMD);
  float var = ss * (1.0f / DIMD) - mu * mu;
  float inv = rsqrtf(var + 1e-5f);
  float2 wv = ((const float2*)w)[tid];
  float2 bv = ((const float2*)bb)[tid];
  short2 o;
  o.x = f2bf((v.x - mu) * inv * wv.x + bv.x);
  o.y = f2bf((v.y - mu) * inv * wv.y + bv.y);
  *(short2*)&xn[(size_t)row * DIMD + tid * 2] = o;
}

// ---------------- m97-style GEMM core (swizzled): 128x128 tile, 4 waves, BK=32 ----------------
__device__ __forceinline__ void gemm_core(const short* __restrict__ A, const short* __restrict__ B,
                                          int lda, int ldb, int K, size_t m0, size_t n0,
                                          int tid, short* sm, f32x4 acc[4][4]) {
  short* As = sm;
  short* Bs = sm + 4096;
  int wid = tid >> 6, lane = tid & 63;
  int wr = (wid >> 1) * 64, wc = (wid & 1) * 64;
  int lr = lane & 15;
  int lk = ((lane >> 4) ^ (lane & 3)) * 8;
  int r0 = tid >> 2;
  int c0 = (((tid & 3) ^ ((tid >> 2) & 3)) & 3) * 8;
  #pragma unroll
  for (int m = 0; m < 4; m++)
    #pragma unroll
    for (int n = 0; n < 4; n++) acc[m][n] = (f32x4){0.f, 0.f, 0.f, 0.f};
  for (int k0 = 0; k0 < K; k0 += 32) {
    gld16(&A[(m0 + r0) * lda + k0 + c0],      &As[wid * 512]);
    gld16(&A[(m0 + 64 + r0) * lda + k0 + c0], &As[2048 + wid * 512]);
    gld16(&B[(n0 + r0) * ldb + k0 + c0],      &Bs[wid * 512]);
    gld16(&B[(n0 + 64 + r0) * ldb + k0 + c0], &Bs[2048 + wid * 512]);
    __syncthreads();
    short8 af[4], bf[4];
    #pragma unroll
    for (int m = 0; m < 4; m++) af[m] = *(short8*)&As[(wr + m * 16 + lr) * 32 + lk];
    #pragma unroll
    for (int n = 0; n < 4; n++) bf[n] = *(short8*)&Bs[(wc + n * 16 + lr) * 32 + lk];
    #pragma unroll
    for (int m = 0; m < 4; m++)
      #pragma unroll
      for (int n = 0; n < 4; n++)
        MFMA16(af[m], bf[n], acc[m][n]);
    __syncthreads();
  }
}

// ============ 256x256 pipelined GEMM core v4 — 2 barriers / 2 waits per K-tile ============
// q1: stage ALL B(t+1) (4); no phase-end sync (Bh(t) staged a full tile ago).
// q2-end: vmcnt(6)+SBAR  (queue Ah(t)2,Al(t+1)2,B(t+1)4 -> drains Ah(t) for q3).
// q3: stage Ah(t+1) (2).  q4: stage Al(t+2) (2) into cur buf;
// q4-end: vmcnt(4)+SBAR  (drains Al(t+1)+B(t+1) = tile t+1's q1/q2 reads).
// Write-safety: every stage-write >=2 barriers after last read of its region,
// except q4's cur-Al write vs q1's Al reads (1 barrier; safe since each wave's
// q1 ds_reads complete (compiler lgkmcnt before MFMA) before it reaches q2-end SBAR).
template<int LD, int T>
__device__ __forceinline__ void core8(const short* __restrict__ A, const short* __restrict__ Bv,
                                      size_t m0, size_t n0, int tid, short* sm,
                                      f32x4 (&acc)[8][4]) {
  const int w = tid >> 6, l = tid & 63;
  const int lr = l & 15;
  const int colsrc = ((l & 7) * 8) ^ ((l >> 3) << 3);
  const short* srcA = A  + (m0 + w * 8 + (l >> 3)) * (size_t)LD + colsrc;
  const short* srcB = Bv + (n0 + w * 8 + (l >> 3)) * (size_t)LD + colsrc;
  const int csw0 = ((l >> 4) * 8) ^ ((l & 7) << 3);
  const int csw1 = (32 + (l >> 4) * 8) ^ ((l & 7) << 3);
  const int AhalfOff = (w >> 2) * 8192 + lr * 64;
  const int BhalfOff = 16384 + ((w & 3) >> 1) * 8192 + ((w & 1) * 64 + lr) * 64;

  #define STA8(bf_, h_, q_, kt_) gld16(srcA + ((h_) * 128 + (q_) * 64) * (size_t)LD + (kt_) * 64, \
                                       &sm[(bf_) * 32768 + (h_) * 8192 + (q_) * 4096 + w * 512])
  #define STB8(bf_, h_, q_, kt_) gld16(srcB + ((h_) * 128 + (q_) * 64) * (size_t)LD + (kt_) * 64, \
                                       &sm[(bf_) * 32768 + 16384 + (h_) * 8192 + (q_) * 4096 + w * 512])

  #pragma unroll
  for (int m = 0; m < 8; m++)
    #pragma unroll
    for (int n = 0; n < 4; n++) acc[m][n] = (f32x4){0.f, 0.f, 0.f, 0.f};
  short8 Af[4][2], Bf0[2][2], Bf1[2][2];

  // prologue: B(0)x4 + Al(0)x2 (drained), then Ah(0)x2 + Al(1)x2 kept in flight
  STB8(0, 0, 0, 0); STB8(0, 1, 0, 0);
  STB8(0, 0, 1, 0); STB8(0, 1, 1, 0);
  STA8(0, 0, 0, 0); STA8(0, 1, 0, 0);
  STA8(0, 0, 1, 0); STA8(0, 1, 1, 0);   // Ah(0)
  STA8(1, 0, 0, 1); STA8(1, 1, 0, 1);   // Al(1)
  VMCNT(4);
  SBAR();
  __builtin_amdgcn_sched_barrier(0);

  for (int t = 0; t < T; ++t) {
    const int buf = t & 1, nb = buf ^ 1;
    short* Ab = sm + buf * 32768 + AhalfOff;
    short* Bb = sm + buf * 32768 + BhalfOff;
    // q1: (mh0,nh0); stage ALL B(t+1); no phase-end sync
    if (t + 1 < T) { STB8(nb, 0, 0, t + 1); STB8(nb, 1, 0, t + 1);
                     STB8(nb, 0, 1, t + 1); STB8(nb, 1, 1, t + 1); }
    #pragma unroll
    for (int i = 0; i < 4; ++i) {
      Af[i][0] = *(const short8*)&Ab[i * 1024 + csw0];
      Af[i][1] = *(const short8*)&Ab[i * 1024 + csw1];
    }
    #pragma unroll
    for (int j = 0; j < 2; ++j) {
      Bf0[j][0] = *(const short8*)&Bb[j * 1024 + csw0];
      Bf0[j][1] = *(const short8*)&Bb[j * 1024 + csw1];
    }
    __builtin_amdgcn_s_setprio(1);
    #pragma unroll
    for (int i = 0; i < 4; ++i)
      #pragma unroll
      for (int j = 0; j < 2; ++j) {
        MFMA16(Af[i][0], Bf0[j][0], acc[i][j]);
        MFMA16(Af[i][1], Bf0[j][1], acc[i][j]);
      }
    __builtin_amdgcn_s_setprio(0);
    // q2: (mh0,nh1); reads B-highs (resident since tile start)
    #pragma unroll
    for (int j = 0; j < 2; ++j) {
      Bf1[j][0] = *(const short8*)&Bb[2048 + j * 1024 + csw0];
      Bf1[j][1] = *(const short8*)&Bb[2048 + j * 1024 + csw1];
    }
    __builtin_amdgcn_s_setprio(1);
    #pragma unroll
    for (int i = 0; i < 4; ++i)
      #pragma unroll
      for (int j = 0; j < 2; ++j) {
        MFMA16(Af[i][0], Bf1[j][0], acc[i][2 + j]);
        MFMA16(Af[i][1], Bf1[j][1], acc[i][2 + j]);
      }
    __builtin_amdgcn_s_setprio(0);
    if (t + 1 < T) { VMCNT(6); } else { VMCNT(0); }   // drains Ah(t) for q3
    SBAR();
    // q3: (mh1,nh1); stage Ah(t+1); no phase-end sync
    if (t + 1 < T) { STA8(nb, 0, 1, t + 1); STA8(nb, 1, 1, t + 1); }
    #pragma unroll
    for (int i = 0; i < 4; ++i) {
      Af[i][0] = *(const short8*)&Ab[4096 + i * 1024 + csw0];
      Af[i][1] = *(const short8*)&Ab[4096 + i * 1024 + csw1];
    }
    __builtin_amdgcn_s_setprio(1);
    #pragma unroll
    for (int i = 0; i < 4; ++i)
      #pragma unroll
      for (int j = 0; j < 2; ++j) {
        MFMA16(Af[i][0], Bf1[j][0], acc[4 + i][2 + j]);
        MFMA16(Af[i][1], Bf1[j][1], acc[4 + i][2 + j]);
      }
    __builtin_amdgcn_s_setprio(0);
    // q4: (mh1,nh0); stage Al(t+2) into cur buf
    if (t + 2 < T) { STA8(buf, 0, 0, t + 2); STA8(buf, 1, 0, t + 2); }
    __builtin_amdgcn_s_setprio(1);
    #pragma unroll
    for (int i = 0; i < 4; ++i)
      #pragma unroll
      for (int j = 0; j < 2; ++j) {
        MFMA16(Af[i][0], Bf0[j][0], acc[4 + i][j]);
        MFMA16(Af[i][1], Bf0[j][1], acc[4 + i][j]);
      }
    __builtin_amdgcn_s_setprio(0);
    if (t + 2 < T) { VMCNT(4); } else if (t + 1 < T) { VMCNT(2); } else { VMCNT(0); }
    SBAR();
    __builtin_amdgcn_sched_barrier(0);
  }
  #undef STA8
  #undef STB8
}

// ---------------- GEMM1: 8-phase 256x256; y==8 is the q/k strip tile ----------------
__global__ __launch_bounds__(512, 2) void guv8_kernel(
    const short* __restrict__ xn, const short* __restrict__ W_uvT,
    const float* __restrict__ b_uv,
    const float* __restrict__ gamma, const float* __restrict__ beta,
    short* __restrict__ u_out, short* __restrict__ vT_out,
    short* __restrict__ q_out, short* __restrict__ k_out)
{
  extern __shared__ __align__(16) short sm[];
  const size_t m0 = (size_t)blockIdx.x * 256;
  const size_t n0 = (size_t)blockIdx.y * 256;
  const int tid = threadIdx.x, w = tid >> 6, l = tid & 63;
  const int lr = l & 15;
  f32x4 acc[8][4];
  core8<DIMD, DIMD / 64>(xn, W_uvT, m0, n0, tid, sm, acc);
  const int rowb0 = (int)m0 + (w >> 2) * 128 + (l >> 4) * 4;
  const int colb0 = (int)n0 + (w & 3) * 64 + lr;
  if (n0 < 1024) {
    #pragma unroll
    for (int mf = 0; mf < 8; ++mf) {
      #pragma unroll
      for (int nf = 0; nf < 4; ++nf) {
        int col = colb0 + nf * 16;
        float bias = b_uv[col];
        #pragma unroll
        for (int r = 0; r < 4; ++r)
          u_out[(size_t)(rowb0 + mf * 16 + r) * EE + col] = f2bf(silu_f(acc[mf][nf][r] + bias));
      }
    }
  } else if (n0 < 2048) {
    #pragma unroll
    for (int mf = 0; mf < 8; ++mf) {
      int row = rowb0 + mf * 16;
      int bb = row >> 12, lb = row & (LLL - 1);
      #pragma unroll
      for (int nf = 0; nf < 4; ++nf) {
        int e = colb0 + nf * 16 - 1024;
        float bias = b_uv[e + 1024];
        short4 o;
        o.x = f2bf(silu_f(acc[mf][nf][0] + bias));
        o.y = f2bf(silu_f(acc[mf][nf][1] + bias));
        o.z = f2bf(silu_f(acc[mf][nf][2] + bias));
        o.w = f2bf(silu_f(acc[mf][nf][3] + bias));
        *(short4*)&vT_out[((size_t)bb * EE + e) * LLL + lb] = o;
      }
    }
  } else {
    if ((w & 3) < 2) {
      const float scale = 0.08838834764831845f;
      #pragma unroll
      for (int mf = 0; mf < 8; ++mf) {
        int rowb = rowb0 + mf * 16;
        #pragma unroll
        for (int nf = 0; nf < 4; ++nf) {
          int s = (w & 3) * 64 + nf * 16 + lr;
          float bias = b_uv[2048 + s];
          float g0 = gamma[s] * scale, g1 = gamma[SSS + s];
          float be0 = beta[s] * scale, be1 = beta[SSS + s];
          #pragma unroll
          for (int r = 0; r < 4; ++r) {
            float val = acc[mf][nf][r] + bias;
            q_out[(size_t)(rowb + r) * SSS + s] = f2bf(val * g0 + be0);
            k_out[(size_t)(rowb + r) * SSS + s] = f2bf(val * g1 + be1);
          }
        }
      }
    }
  }
}

// ---------------- QK^T 256x256 single-stage: whole K=128 resident in LDS ----------------
__global__ __launch_bounds__(512, 2) void gqk4_kernel(
    const short* __restrict__ q, const short* __restrict__ k, short* __restrict__ P)
{
  extern __shared__ __align__(16) short sm[];
  const int b = blockIdx.z;
  const size_t m0 = (size_t)blockIdx.x * 256;
  const size_t n0 = (size_t)blockIdx.y * 256;
  const short* qz = q + (size_t)b * LLL * SSS;
  const short* kz = k + (size_t)b * LLL * SSS;
  short* Pz = P + (size_t)b * LLL * LLL;
  const int tid = threadIdx.x, w = tid >> 6, l = tid & 63;
  const int lr = l & 15;
  const int srow4 = w * 4 + (l >> 4);
  #pragma unroll
  for (int u = 0; u < 8; ++u) {
    int row = u * 32 + srow4;
    int scol = ((l & 15) * 8) ^ ((row & 7) << 3);
    gld16(qz + (m0 + row) * SSS + scol, &sm[(u * 32 + w * 4) * 128]);
    gld16(kz + (n0 + row) * SSS + scol, &sm[32768 + (u * 32 + w * 4) * 128]);
  }
  f32x4 acc[8][4];
  #pragma unroll
  for (int m = 0; m < 8; m++)
    #pragma unroll
    for (int n = 0; n < 4; n++) acc[m][n] = (f32x4){0.f, 0.f, 0.f, 0.f};
  VMCNT(0);
  __syncthreads();
  const int wr = (w >> 2) * 128, wc = (w & 3) * 64;
  #pragma unroll
  for (int ks = 0; ks < 4; ++ks) {
    const int csw = (ks * 32 + (l >> 4) * 8) ^ ((l & 7) << 3);
    short8 af[8], bf[4];
    #pragma unroll
    for (int m = 0; m < 8; m++) af[m] = *(const short8*)&sm[(wr + m * 16 + lr) * 128 + csw];
    #pragma unroll
    for (int n = 0; n < 4; n++) bf[n] = *(const short8*)&sm[32768 + (wc + n * 16 + lr) * 128 + csw];
    #pragma unroll
    for (int m = 0; m < 8; m++)
      #pragma unroll
      for (int n = 0; n < 4; n++)
        MFMA16(af[m], bf[n], acc[m][n]);
  }
  const int rowb0 = (int)m0 + wr + (l >> 4) * 4;
  const int colb0 = (int)n0 + wc + lr;
  #pragma unroll
  for (int mf = 0; mf < 8; mf++) {
    #pragma unroll
    for (int nf = 0; nf < 4; nf++) {
      int col = colb0 + nf * 16;
      #pragma unroll
      for (int r = 0; r < 4; r++) {
        float v = fmaxf(acc[mf][nf][r], 0.f);
        Pz[(size_t)(rowb0 + mf * 16 + r) * LLL + col] = f2bf(v * v);
      }
    }
  }
}

// ---------------- legacy QK (fallback tiers; q pre-scaled; row-major P) ----------------
__global__ __launch_bounds__(256) void gqk_kernel(
    const short* __restrict__ q, const short* __restrict__ k, short* __restrict__ P,
    long sq, long sk, long sp)
{
  __shared__ __align__(16) short sm[8192];
  int tid = threadIdx.x;
  const short* qz = q + (size_t)blockIdx.z * sq;
  const short* kz = k + (size_t)blockIdx.z * sk;
  short* Pz = P + (size_t)blockIdx.z * sp;
  size_t m0 = (size_t)blockIdx.x * 128, n0 = (size_t)blockIdx.y * 128;
  f32x4 acc[4][4];
  gemm_core(qz, kz, SSS, SSS, SSS, m0, n0, tid, sm, acc);
  int wid = tid >> 6, lane = tid & 63;
  int wr = (wid >> 1) * 64, wc = (wid & 1) * 64;
  int lr = lane & 15;
  #pragma unroll
  for (int m = 0; m < 4; m++) {
    #pragma unroll
    for (int n = 0; n < 4; n++) {
      int col = (int)n0 + wc + n * 16 + lr;
      int rowb = (int)m0 + wr + m * 16 + (lane >> 4) * 4;
      #pragma unroll
      for (int r = 0; r < 4; r++) {
        float v = fmaxf(acc[m][n][r], 0.f);
        Pz[(size_t)(rowb + r) * LLL + col] = f2bf(v * v);
      }
    }
  }
}

// ---------------- legacy PV (fallback tiers): m97 core, row-major P ----------------
__global__ __launch_bounds__(256) void gpv_kernel(
    const short* __restrict__ P, const short* __restrict__ vT,
    const short* __restrict__ u, short* __restrict__ g,
    long sp, long sv, long su)
{
  __shared__ __align__(16) short sm[8192];
  int tid = threadIdx.x;
  const short* Pz = P + (size_t)blockIdx.z * sp;
  const short* vz = vT + (size_t)blockIdx.z * sv;
  const short* uz = u + (size_t)blockIdx.z * su;
  short* gz = g + (size_t)blockIdx.z * su;
  size_t m0 = (size_t)blockIdx.x * 128, n0 = (size_t)blockIdx.y * 128;
  f32x4 acc[4][4];
  gemm_core(Pz, vz, LLL, LLL, LLL, m0, n0, tid, sm, acc);
  int wid = tid >> 6, lane = tid & 63;
  int wr = (wid >> 1) * 64, wc = (wid & 1) * 64;
  int lr = lane & 15;
  #pragma unroll
  for (int m = 0; m < 4; m++) {
    #pragma unroll
    for (int n = 0; n < 4; n++) {
      int col = (int)n0 + wc + n * 16 + lr;
      int rowb = (int)m0 + wr + m * 16 + (lane >> 4) * 4;
      #pragma unroll
      for (int r = 0; r < 4; r++) {
        size_t idx = (size_t)(rowb + r) * EE + col;
        gz[idx] = f2bf(bf2f(uz[idx]) * acc[m][n][r]);
      }
    }
  }
}

// ---------------- PV, 256x256 (core8 v4) ----------------
__global__ __launch_bounds__(512, 2) void gpv8_kernel(
    const short* __restrict__ Pg, const short* __restrict__ vTg,
    const short* __restrict__ ug, short* __restrict__ gg)
{
  extern __shared__ __align__(16) short sm[];
  const int b = blockIdx.z;
  const size_t m0 = (size_t)blockIdx.x * 256;
  const size_t n0 = (size_t)blockIdx.y * 256;
  const short* A  = Pg  + (size_t)b * LLL * LLL;
  const short* Bv = vTg + (size_t)b * EE * LLL;
  const int tid = threadIdx.x, w = tid >> 6, l = tid & 63;
  const int lr = l & 15;
  f32x4 acc[8][4];
  core8<LLL, LLL / 64>(A, Bv, m0, n0, tid, sm, acc);
  const short* ub_ = ug + (size_t)b * LLL * EE;
  short* gb_ = gg + (size_t)b * LLL * EE;
  const int rowb0 = (int)m0 + (w >> 2) * 128 + (l >> 4) * 4;
  const int colb0 = (int)n0 + (w & 3) * 64 + lr;
  #pragma unroll
  for (int mf = 0; mf < 8; ++mf) {
    #pragma unroll
    for (int nf = 0; nf < 4; ++nf) {
      int col = colb0 + nf * 16;
      #pragma unroll
      for (int r = 0; r < 4; ++r) {
        size_t idx = (size_t)(rowb0 + mf * 16 + r) * EE + col;
        gb_[idx] = f2bf(bf2f(ub_[idx]) * acc[mf][nf][r]);
      }
    }
  }
}

// ---------------- GEMM2 v2: 256x128 tile, 3-buf rotation, 1 barrier/K-tile ----------------
__global__ __launch_bounds__(512, 1) void gout2_kernel(
    const short* __restrict__ A, const short* __restrict__ Bw,
    const float* __restrict__ b_out, const float* __restrict__ x,
    float* __restrict__ out)
{
  extern __shared__ __align__(16) short sm[];
  const size_t m0 = (size_t)blockIdx.x * 256;
  const size_t n0 = (size_t)blockIdx.y * 128;
  const int tid = threadIdx.x, w = tid >> 6, l = tid & 63;
  const int lr = l & 15;
  const int colsrc = ((l & 7) * 8) ^ ((l >> 3) << 3);
  const short* srcA = A  + (m0 + w * 8 + (l >> 3)) * (size_t)EE + colsrc;
  const short* srcB = Bw + (n0 + w * 8 + (l >> 3)) * (size_t)EE + colsrc;
  const int csw0 = ((l >> 4) * 8) ^ ((l & 7) << 3);
  const int csw1 = (32 + (l >> 4) * 8) ^ ((l & 7) << 3);
  const int mq = w >> 1, nh = w & 1;
  const int ARd = (mq * 64 + lr) * 64;
  const int BRd = 16384 + (nh * 64 + lr) * 64;

  #define GSTA(r_, u_, kt_) gld16(srcA + (u_) * 64 * (size_t)EE + (kt_) * 64, \
                                  &sm[(r_) * 24576 + (u_) * 4096 + w * 512])
  #define GSTB(r_, u_, kt_) gld16(srcB + (u_) * 64 * (size_t)EE + (kt_) * 64, \
                                  &sm[(r_) * 24576 + 16384 + (u_) * 4096 + w * 512])

  f32x4 acc[4][4];
  #pragma unroll
  for (int m = 0; m < 4; m++)
    #pragma unroll
    for (int n = 0; n < 4; n++) acc[m][n] = (f32x4){0.f, 0.f, 0.f, 0.f};

  GSTA(0, 0, 0); GSTA(0, 1, 0); GSTA(0, 2, 0); GSTA(0, 3, 0); GSTB(0, 0, 0); GSTB(0, 1, 0);
  GSTA(1, 0, 1); GSTA(1, 1, 1); GSTA(1, 2, 1); GSTA(1, 3, 1); GSTB(1, 0, 1); GSTB(1, 1, 1);
  VMCNT(6);
  SBAR();
  __builtin_amdgcn_sched_barrier(0);

  const int T = EE / 64;   // 16
  for (int t = 0; t < T; ++t) {
    const int r = t % 3, n2 = (t + 2) % 3;
    const short* Ab = sm + r * 24576 + ARd;
    const short* Bb = sm + r * 24576 + BRd;
    short8 af[4], bf[4];
    if (t + 2 < T) { GSTA(n2, 0, t + 2); GSTA(n2, 1, t + 2); GSTB(n2, 0, t + 2); }
    #pragma unroll
    for (int i = 0; i < 4; ++i) af[i] = *(const short8*)&Ab[i * 1024 + csw0];
    #pragma unroll
    for (int j = 0; j < 4; ++j) bf[j] = *(const short8*)&Bb[j * 1024 + csw0];
    __builtin_amdgcn_s_setprio(1);
    #pragma unroll
    for (int i = 0; i < 4; ++i)
      #pragma unroll
      for (int j = 0; j < 4; ++j)
        MFMA16(af[i], bf[j], acc[i][j]);
    __builtin_amdgcn_s_setprio(0);
    if (t + 2 < T) { GSTA(n2, 2, t + 2); GSTA(n2, 3, t + 2); GSTB(n2, 1, t + 2); }
    #pragma unroll
    for (int i = 0; i < 4; ++i) af[i] = *(const short8*)&Ab[i * 1024 + csw1];
    #pragma unroll
    for (int j = 0; j < 4; ++j) bf[j] = *(const short8*)&Bb[j * 1024 + csw1];
    __builtin_amdgcn_s_setprio(1);
    #pragma unroll
    for (int i = 0; i < 4; ++i)
      #pragma unroll
      for (int j = 0; j < 4; ++j)
        MFMA16(af[i], bf[j], acc[i][j]);
    __builtin_amdgcn_s_setprio(0);
    if (t + 2 < T) { VMCNT(6); } else { VMCNT(0); }
    SBAR();
    __builtin_amdgcn_sched_barrier(0);
  }
  #undef GSTA
  #undef GSTB

  const int rowb0 = (int)m0 + mq * 64 + (l >> 4) * 4;
  const int colb0 = (int)n0 + nh * 64 + lr;
  #pragma unroll
  for (int i = 0; i < 4; ++i) {
    #pragma unroll
    for (int j = 0; j < 4; ++j) {
      int col = colb0 + j * 16;
      float bias = b_out[col];
      #pragma unroll
      for (int r = 0; r < 4; ++r) {
        size_t idx = (size_t)(rowb0 + i * 16 + r) * DIMD + col;
        out[idx] = acc[i][j][r] + bias + x[idx];
      }
    }
  }
}

extern "C" void kernel_launch(void* const* d_in, const int* in_sizes, int n_in,
                              void* d_out, int out_size, void* d_ws, size_t ws_size,
                              hipStream_t stream) {
  const float* x     = (const float*)d_in[0];
  const float* W_uv  = (const float*)d_in[1];
  const float* b_uv  = (const float*)d_in[2];
  const float* gamma = (const float*)d_in[3];
  const float* beta  = (const float*)d_in[4];
  const float* W_out = (const float*)d_in[5];
  const float* b_out = (const float*)d_in[6];
  const float* ln_w  = (const float*)d_in[7];
  const float* ln_b  = (const float*)d_in[8];
  float* out = (float*)d_out;

  char* ws = (char*)d_ws;
  short* W_uvT  = (short*)(ws);
  short* W_outT = (short*)(ws + 2228224);
  short* xn     = (short*)(ws + 3276800);
  short* qb     = (short*)(ws + 20054016);
  short* kb     = (short*)(ws + 24248320);
  short* ub     = (short*)(ws + 28442624);
  short* vTb    = (short*)(ws + 61997056);
  short* gb     = (short*)(ws + 95551488);
  short* Pb     = (short*)(ws + 129105920);

  prepln_kernel<<<dim3(NROW + 400), 256, 0, stream>>>(
      x, ln_w, ln_b, xn, W_uv, W_out, W_uvT, W_outT);
  guv8_kernel<<<dim3(NROW / 256, 9), 512, 131072, stream>>>(
      xn, W_uvT, b_uv, gamma, beta, ub, vTb, qb, kb);

  const long SQ = (long)LLL * SSS;
  const long SP = (long)LLL * LLL;
  const long SV = (long)EE * LLL;
  const long SU = (long)LLL * EE;

  if (ws_size >= 129105920ull + 134217728ull) {
    gqk4_kernel<<<dim3(16, 16, 4), 512, 131072, stream>>>(qb, kb, Pb);
    gpv8_kernel<<<dim3(16, 4, 4), 512, 131072, stream>>>(Pb, vTb, ub, gb);
  } else if (ws_size >= 129105920ull + 33554432ull) {
    for (int b = 0; b < 4; b++) {
      gqk_kernel<<<dim3(32, 32, 1), 256, 0, stream>>>(qb + (size_t)b * SQ, kb + (size_t)b * SQ, Pb, 0, 0, 0);
      gpv_kernel<<<dim3(32, 8, 1), 256, 0, stream>>>(Pb, vTb + (size_t)b * SV, ub + (size_t)b * SU, gb + (size_t)b * SU, 0, 0, 0);
    }
  } else {
    short* Pc = xn;
    for (int b = 0; b < 4; b++) {
      for (int h = 0; h < 2; h++) {
        size_t rowoff = (size_t)b * LLL + (size_t)h * 2048;
        gqk_kernel<<<dim3(16, 32, 1), 256, 0, stream>>>(qb + rowoff * SSS, kb + (size_t)b * SQ, Pc, 0, 0, 0);
        gpv_kernel<<<dim3(16, 8, 1), 256, 0, stream>>>(Pc, vTb + (size_t)b * SV, ub + rowoff * EE, gb + rowoff * EE, 0, 0, 0);
      }
    }
  }

  gout2_kernel<<<dim3(NROW / 256, DIMD / 128), 512, 147456, stream>>>(gb, W_outT, b_out, x, out);
}

// Round 17
// 268.089 us; speedup vs baseline: 1.0251x; 1.0251x over previous
//
#include <hip/hip_runtime.h>

typedef __attribute__((ext_vector_type(8))) short short8;
typedef __attribute__((ext_vector_type(4))) float f32x4;

#define DIMD 512
#define EE 1024
#define SSS 128
#define LLL 4096
#define NROW 16384   // B*L
#define NUV 2176     // 2E+S

__device__ __forceinline__ short f2bf(float f) {
  union { float f; unsigned u; } un; un.f = f;
  unsigned r = un.u + 0x7FFFu + ((un.u >> 16) & 1u);
  return (short)(r >> 16);
}
__device__ __forceinline__ float bf2f(short s) {
  union { unsigned u; float f; } un;
  un.u = ((unsigned)(unsigned short)s) << 16;
  return un.f;
}
__device__ __forceinline__ float silu_f(float x) {
  return x / (1.0f + __expf(-x));
}

__device__ __forceinline__ void gld16(const short* g, short* l) {
  __builtin_amdgcn_global_load_lds(
      (const __attribute__((address_space(1))) unsigned int*)g,
      (__attribute__((address_space(3))) unsigned int*)l, 16, 0, 0);
}

#define MFMA16(a, b, c) c = __builtin_amdgcn_mfma_f32_16x16x32_bf16(a, b, c, 0, 0, 0)
#define SBAR() asm volatile("s_barrier" ::: "memory")
#define VMCNT(n) asm volatile("s_waitcnt vmcnt(" #n ")" ::: "memory")

// ---------------- fused prep+layernorm ----------------
__global__ __launch_bounds__(256) void prepln_kernel(
    const float* __restrict__ x, const float* __restrict__ w, const float* __restrict__ bb,
    short* __restrict__ xn,
    const float* __restrict__ W_uv, const float* __restrict__ W_out,
    short* __restrict__ W_uvT, short* __restrict__ W_outT) {
  int tid = threadIdx.x;
  int bx = blockIdx.x;
  if (bx >= NROW) {
    __shared__ float tile[64][65];
    int wb = bx - NROW;
    const float* src; short* dst; int s0, c0, ldS, ldD;
    if (wb < 272) {
      int dt = wb / 34, ct = wb - dt * 34;
      s0 = dt * 64; c0 = ct * 64; ldS = NUV; ldD = DIMD;
      src = W_uv; dst = W_uvT;
    } else {
      int wb2 = wb - 272;
      int et = wb2 >> 3, dt = wb2 & 7;
      s0 = et * 64; c0 = dt * 64; ldS = DIMD; ldD = EE;
      src = W_out; dst = W_outT;
    }
    int r0 = tid >> 6, c = tid & 63;
    #pragma unroll
    for (int rr = 0; rr < 16; ++rr) {
      int row = rr * 4 + r0;
      tile[row][c] = src[(size_t)(s0 + row) * ldS + c0 + c];
    }
    __syncthreads();
    #pragma unroll
    for (int rr = 0; rr < 16; ++rr) {
      int row = rr * 4 + r0;
      dst[(size_t)(c0 + row) * ldD + s0 + c] = f2bf(tile[c][row]);
    }
    return;
  }
  int row = bx;
  const float2* xr = (const float2*)(x + (size_t)row * DIMD);
  float2 v = xr[tid];
  float s = v.x + v.y, ss = v.x * v.x + v.y * v.y;
  #pragma unroll
  for (int off = 32; off >= 1; off >>= 1) {
    s += __shfl_down(s, off);
    ss += __shfl_down(ss, off);
  }
  __shared__ float ps[8];
  if ((tid & 63) == 0) { ps[tid >> 6] = s; ps[4 + (tid >> 6)] = ss; }
  __syncthreads();
  s = ps[0] + ps[1] + ps[2] + ps[3];
  ss = ps[4] + ps[5] + ps[6] + ps[7];
  float mu = s * (1.0f / DIMD);
  float var = ss * (1.0f / DIMD) - mu * mu;
  float inv = rsqrtf(var + 1e-5f);
  float2 wv = ((const float2*)w)[tid];
  float2 bv = ((const float2*)bb)[tid];
  short2 o;
  o.x = f2bf((v.x - mu) * inv * wv.x + bv.x);
  o.y = f2bf((v.y - mu) * inv * wv.y + bv.y);
  *(short2*)&xn[(size_t)row * DIMD + tid * 2] = o;
}

// ---------------- m97-style GEMM core (swizzled): 128x128 tile, 4 waves, BK=32 ----------------
__device__ __forceinline__ void gemm_core(const short* __restrict__ A, const short* __restrict__ B,
                                          int lda, int ldb, int K, size_t m0, size_t n0,
                                          int tid, short* sm, f32x4 acc[4][4]) {
  short* As = sm;
  short* Bs = sm + 4096;
  int wid = tid >> 6, lane = tid & 63;
  int wr = (wid >> 1) * 64, wc = (wid & 1) * 64;
  int lr = lane & 15;
  int lk = ((lane >> 4) ^ (lane & 3)) * 8;
  int r0 = tid >> 2;
  int c0 = (((tid & 3) ^ ((tid >> 2) & 3)) & 3) * 8;
  #pragma unroll
  for (int m = 0; m < 4; m++)
    #pragma unroll
    for (int n = 0; n < 4; n++) acc[m][n] = (f32x4){0.f, 0.f, 0.f, 0.f};
  for (int k0 = 0; k0 < K; k0 += 32) {
    gld16(&A[(m0 + r0) * lda + k0 + c0],      &As[wid * 512]);
    gld16(&A[(m0 + 64 + r0) * lda + k0 + c0], &As[2048 + wid * 512]);
    gld16(&B[(n0 + r0) * ldb + k0 + c0],      &Bs[wid * 512]);
    gld16(&B[(n0 + 64 + r0) * ldb + k0 + c0], &Bs[2048 + wid * 512]);
    __syncthreads();
    short8 af[4], bf[4];
    #pragma unroll
    for (int m = 0; m < 4; m++) af[m] = *(short8*)&As[(wr + m * 16 + lr) * 32 + lk];
    #pragma unroll
    for (int n = 0; n < 4; n++) bf[n] = *(short8*)&Bs[(wc + n * 16 + lr) * 32 + lk];
    #pragma unroll
    for (int m = 0; m < 4; m++)
      #pragma unroll
      for (int n = 0; n < 4; n++)
        MFMA16(af[m], bf[n], acc[m][n]);
    __syncthreads();
  }
}

// ============ 256x256 8-phase pipelined GEMM core — R5 schedule, 3 barriers/tile ============
// (best measured config, R15: gpv8 119.5us / MfmaUtil 48.6)
template<int LD, int T>
__device__ __forceinline__ void core8(const short* __restrict__ A, const short* __restrict__ Bv,
                                      size_t m0, size_t n0, int tid, short* sm,
                                      f32x4 (&acc)[8][4]) {
  const int w = tid >> 6, l = tid & 63;
  const int lr = l & 15;
  const int colsrc = ((l & 7) * 8) ^ ((l >> 3) << 3);
  const short* srcA = A  + (m0 + w * 8 + (l >> 3)) * (size_t)LD + colsrc;
  const short* srcB = Bv + (n0 + w * 8 + (l >> 3)) * (size_t)LD + colsrc;
  const int csw0 = ((l >> 4) * 8) ^ ((l & 7) << 3);
  const int csw1 = (32 + (l >> 4) * 8) ^ ((l & 7) << 3);
  const int AhalfOff = (w >> 2) * 8192 + lr * 64;
  const int BhalfOff = 16384 + ((w & 3) >> 1) * 8192 + ((w & 1) * 64 + lr) * 64;

  #define STA8(bf_, h_, q_, kt_) gld16(srcA + ((h_) * 128 + (q_) * 64) * (size_t)LD + (kt_) * 64, \
                                       &sm[(bf_) * 32768 + (h_) * 8192 + (q_) * 4096 + w * 512])
  #define STB8(bf_, h_, q_, kt_) gld16(srcB + ((h_) * 128 + (q_) * 64) * (size_t)LD + (kt_) * 64, \
                                       &sm[(bf_) * 32768 + 16384 + (h_) * 8192 + (q_) * 4096 + w * 512])

  #pragma unroll
  for (int m = 0; m < 8; m++)
    #pragma unroll
    for (int n = 0; n < 4; n++) acc[m][n] = (f32x4){0.f, 0.f, 0.f, 0.f};
  short8 Af[4][2], Bf0[2][2], Bf1[2][2];

  STA8(0, 0, 0, 0); STA8(0, 1, 0, 0);
  STB8(0, 0, 0, 0); STB8(0, 1, 0, 0);
  STB8(0, 0, 1, 0); STB8(0, 1, 1, 0);
  STA8(0, 0, 1, 0); STA8(0, 1, 1, 0);
  STA8(1, 0, 0, 1); STA8(1, 1, 0, 1);
  VMCNT(2);
  SBAR();
  __builtin_amdgcn_sched_barrier(0);

  for (int t = 0; t < T; ++t) {
    const int buf = t & 1, nb = buf ^ 1;
    short* Ab = sm + buf * 32768 + AhalfOff;
    short* Bb = sm + buf * 32768 + BhalfOff;
    // q1: (mh0,nh0); stage Bl(t+1)
    if (t + 1 < T) { STB8(nb, 0, 0, t + 1); STB8(nb, 1, 0, t + 1); }
    #pragma unroll
    for (int i = 0; i < 4; ++i) {
      Af[i][0] = *(const short8*)&Ab[i * 1024 + csw0];
      Af[i][1] = *(const short8*)&Ab[i * 1024 + csw1];
    }
    #pragma unroll
    for (int j = 0; j < 2; ++j) {
      Bf0[j][0] = *(const short8*)&Bb[j * 1024 + csw0];
      Bf0[j][1] = *(const short8*)&Bb[j * 1024 + csw1];
    }
    __builtin_amdgcn_s_setprio(1);
    #pragma unroll
    for (int i = 0; i < 4; ++i)
      #pragma unroll
      for (int j = 0; j < 2; ++j) {
        MFMA16(Af[i][0], Bf0[j][0], acc[i][j]);
        MFMA16(Af[i][1], Bf0[j][1], acc[i][j]);
      }
    __builtin_amdgcn_s_setprio(0);
    if (t + 1 < T) { VMCNT(6); } else { VMCNT(2); }
    SBAR();
    // q2: (mh0,nh1); stage Bh(t+1)
    if (t + 1 < T) { STB8(nb, 0, 1, t + 1); STB8(nb, 1, 1, t + 1); }
    #pragma unroll
    for (int j = 0; j < 2; ++j) {
      Bf1[j][0] = *(const short8*)&Bb[2048 + j * 1024 + csw0];
      Bf1[j][1] = *(const short8*)&Bb[2048 + j * 1024 + csw1];
    }
    __builtin_amdgcn_s_setprio(1);
    #pragma unroll
    for (int i = 0; i < 4; ++i)
      #pragma unroll
      for (int j = 0; j < 2; ++j) {
        MFMA16(Af[i][0], Bf1[j][0], acc[i][2 + j]);
        MFMA16(Af[i][1], Bf1[j][1], acc[i][2 + j]);
      }
    __builtin_amdgcn_s_setprio(0);
    if (t + 1 < T) { VMCNT(6); } else { VMCNT(0); }
    SBAR();
    // q3: (mh1,nh1); stage Ah(t+1)  [no phase-end barrier]
    if (t + 1 < T) { STA8(nb, 0, 1, t + 1); STA8(nb, 1, 1, t + 1); }
    #pragma unroll
    for (int i = 0; i < 4; ++i) {
      Af[i][0] = *(const short8*)&Ab[4096 + i * 1024 + csw0];
      Af[i][1] = *(const short8*)&Ab[4096 + i * 1024 + csw1];
    }
    __builtin_amdgcn_s_setprio(1);
    #pragma unroll
    for (int i = 0; i < 4; ++i)
      #pragma unroll
      for (int j = 0; j < 2; ++j) {
        MFMA16(Af[i][0], Bf1[j][0], acc[4 + i][2 + j]);
        MFMA16(Af[i][1], Bf1[j][1], acc[4 + i][2 + j]);
      }
    __builtin_amdgcn_s_setprio(0);
    // q4: (mh1,nh0); stage Al(t+2) into cur buf
    if (t + 2 < T) { STA8(buf, 0, 0, t + 2); STA8(buf, 1, 0, t + 2); }
    __builtin_amdgcn_s_setprio(1);
    #pragma unroll
    for (int i = 0; i < 4; ++i)
      #pragma unroll
      for (int j = 0; j < 2; ++j) {
        MFMA16(Af[i][0], Bf0[j][0], acc[4 + i][j]);
        MFMA16(Af[i][1], Bf0[j][1], acc[4 + i][j]);
      }
    __builtin_amdgcn_s_setprio(0);
    if (t + 2 < T) { VMCNT(6); } else if (t + 1 < T) { VMCNT(4); } else { VMCNT(0); }
    SBAR();
    __builtin_amdgcn_sched_barrier(0);
  }
  #undef STA8
  #undef STB8
}

// ---------------- GEMM1: 8-phase 256x256; y==8 is the q/k strip tile ----------------
__global__ __launch_bounds__(512, 2) void guv8_kernel(
    const short* __restrict__ xn, const short* __restrict__ W_uvT,
    const float* __restrict__ b_uv,
    const float* __restrict__ gamma, const float* __restrict__ beta,
    short* __restrict__ u_out, short* __restrict__ vT_out,
    short* __restrict__ q_out, short* __restrict__ k_out)
{
  extern __shared__ __align__(16) short sm[];
  const size_t m0 = (size_t)blockIdx.x * 256;
  const size_t n0 = (size_t)blockIdx.y * 256;
  const int tid = threadIdx.x, w = tid >> 6, l = tid & 63;
  const int lr = l & 15;
  f32x4 acc[8][4];
  core8<DIMD, DIMD / 64>(xn, W_uvT, m0, n0, tid, sm, acc);
  const int rowb0 = (int)m0 + (w >> 2) * 128 + (l >> 4) * 4;
  const int colb0 = (int)n0 + (w & 3) * 64 + lr;
  if (n0 < 1024) {
    #pragma unroll
    for (int mf = 0; mf < 8; ++mf) {
      #pragma unroll
      for (int nf = 0; nf < 4; ++nf) {
        int col = colb0 + nf * 16;
        float bias = b_uv[col];
        #pragma unroll
        for (int r = 0; r < 4; ++r)
          u_out[(size_t)(rowb0 + mf * 16 + r) * EE + col] = f2bf(silu_f(acc[mf][nf][r] + bias));
      }
    }
  } else if (n0 < 2048) {
    #pragma unroll
    for (int mf = 0; mf < 8; ++mf) {
      int row = rowb0 + mf * 16;
      int bb = row >> 12, lb = row & (LLL - 1);
      #pragma unroll
      for (int nf = 0; nf < 4; ++nf) {
        int e = colb0 + nf * 16 - 1024;
        float bias = b_uv[e + 1024];
        short4 o;
        o.x = f2bf(silu_f(acc[mf][nf][0] + bias));
        o.y = f2bf(silu_f(acc[mf][nf][1] + bias));
        o.z = f2bf(silu_f(acc[mf][nf][2] + bias));
        o.w = f2bf(silu_f(acc[mf][nf][3] + bias));
        *(short4*)&vT_out[((size_t)bb * EE + e) * LLL + lb] = o;
      }
    }
  } else {
    if ((w & 3) < 2) {
      const float scale = 0.08838834764831845f;
      #pragma unroll
      for (int mf = 0; mf < 8; ++mf) {
        int rowb = rowb0 + mf * 16;
        #pragma unroll
        for (int nf = 0; nf < 4; ++nf) {
          int s = (w & 3) * 64 + nf * 16 + lr;
          float bias = b_uv[2048 + s];
          float g0 = gamma[s] * scale, g1 = gamma[SSS + s];
          float be0 = beta[s] * scale, be1 = beta[SSS + s];
          #pragma unroll
          for (int r = 0; r < 4; ++r) {
            float val = acc[mf][nf][r] + bias;
            q_out[(size_t)(rowb + r) * SSS + s] = f2bf(val * g0 + be0);
            k_out[(size_t)(rowb + r) * SSS + s] = f2bf(val * g1 + be1);
          }
        }
      }
    }
  }
}

// ---------------- QK^T 256x256 single-stage: whole K=128 resident in LDS ----------------
__global__ __launch_bounds__(512, 2) void gqk4_kernel(
    const short* __restrict__ q, const short* __restrict__ k, short* __restrict__ P)
{
  extern __shared__ __align__(16) short sm[];
  const int b = blockIdx.z;
  const size_t m0 = (size_t)blockIdx.x * 256;
  const size_t n0 = (size_t)blockIdx.y * 256;
  const short* qz = q + (size_t)b * LLL * SSS;
  const short* kz = k + (size_t)b * LLL * SSS;
  short* Pz = P + (size_t)b * LLL * LLL;
  const int tid = threadIdx.x, w = tid >> 6, l = tid & 63;
  const int lr = l & 15;
  const int srow4 = w * 4 + (l >> 4);
  #pragma unroll
  for (int u = 0; u < 8; ++u) {
    int row = u * 32 + srow4;
    int scol = ((l & 15) * 8) ^ ((row & 7) << 3);
    gld16(qz + (m0 + row) * SSS + scol, &sm[(u * 32 + w * 4) * 128]);
    gld16(kz + (n0 + row) * SSS + scol, &sm[32768 + (u * 32 + w * 4) * 128]);
  }
  f32x4 acc[8][4];
  #pragma unroll
  for (int m = 0; m < 8; m++)
    #pragma unroll
    for (int n = 0; n < 4; n++) acc[m][n] = (f32x4){0.f, 0.f, 0.f, 0.f};
  VMCNT(0);
  __syncthreads();
  const int wr = (w >> 2) * 128, wc = (w & 3) * 64;
  #pragma unroll
  for (int ks = 0; ks < 4; ++ks) {
    const int csw = (ks * 32 + (l >> 4) * 8) ^ ((l & 7) << 3);
    short8 af[8], bf[4];
    #pragma unroll
    for (int m = 0; m < 8; m++) af[m] = *(const short8*)&sm[(wr + m * 16 + lr) * 128 + csw];
    #pragma unroll
    for (int n = 0; n < 4; n++) bf[n] = *(const short8*)&sm[32768 + (wc + n * 16 + lr) * 128 + csw];
    #pragma unroll
    for (int m = 0; m < 8; m++)
      #pragma unroll
      for (int n = 0; n < 4; n++)
        MFMA16(af[m], bf[n], acc[m][n]);
  }
  const int rowb0 = (int)m0 + wr + (l >> 4) * 4;
  const int colb0 = (int)n0 + wc + lr;
  #pragma unroll
  for (int mf = 0; mf < 8; mf++) {
    #pragma unroll
    for (int nf = 0; nf < 4; nf++) {
      int col = colb0 + nf * 16;
      #pragma unroll
      for (int r = 0; r < 4; r++) {
        float v = fmaxf(acc[mf][nf][r], 0.f);
        Pz[(size_t)(rowb0 + mf * 16 + r) * LLL + col] = f2bf(v * v);
      }
    }
  }
}

// ---------------- legacy QK (fallback tiers; q pre-scaled; row-major P) ----------------
__global__ __launch_bounds__(256) void gqk_kernel(
    const short* __restrict__ q, const short* __restrict__ k, short* __restrict__ P,
    long sq, long sk, long sp)
{
  __shared__ __align__(16) short sm[8192];
  int tid = threadIdx.x;
  const short* qz = q + (size_t)blockIdx.z * sq;
  const short* kz = k + (size_t)blockIdx.z * sk;
  short* Pz = P + (size_t)blockIdx.z * sp;
  size_t m0 = (size_t)blockIdx.x * 128, n0 = (size_t)blockIdx.y * 128;
  f32x4 acc[4][4];
  gemm_core(qz, kz, SSS, SSS, SSS, m0, n0, tid, sm, acc);
  int wid = tid >> 6, lane = tid & 63;
  int wr = (wid >> 1) * 64, wc = (wid & 1) * 64;
  int lr = lane & 15;
  #pragma unroll
  for (int m = 0; m < 4; m++) {
    #pragma unroll
    for (int n = 0; n < 4; n++) {
      int col = (int)n0 + wc + n * 16 + lr;
      int rowb = (int)m0 + wr + m * 16 + (lane >> 4) * 4;
      #pragma unroll
      for (int r = 0; r < 4; r++) {
        float v = fmaxf(acc[m][n][r], 0.f);
        Pz[(size_t)(rowb + r) * LLL + col] = f2bf(v * v);
      }
    }
  }
}

// ---------------- legacy PV (fallback tiers): m97 core, row-major P ----------------
__global__ __launch_bounds__(256) void gpv_kernel(
    const short* __restrict__ P, const short* __restrict__ vT,
    const short* __restrict__ u, short* __restrict__ g,
    long sp, long sv, long su)
{
  __shared__ __align__(16) short sm[8192];
  int tid = threadIdx.x;
  const short* Pz = P + (size_t)blockIdx.z * sp;
  const short* vz = vT + (size_t)blockIdx.z * sv;
  const short* uz = u + (size_t)blockIdx.z * su;
  short* gz = g + (size_t)blockIdx.z * su;
  size_t m0 = (size_t)blockIdx.x * 128, n0 = (size_t)blockIdx.y * 128;
  f32x4 acc[4][4];
  gemm_core(Pz, vz, LLL, LLL, LLL, m0, n0, tid, sm, acc);
  int wid = tid >> 6, lane = tid & 63;
  int wr = (wid >> 1) * 64, wc = (wid & 1) * 64;
  int lr = lane & 15;
  #pragma unroll
  for (int m = 0; m < 4; m++) {
    #pragma unroll
    for (int n = 0; n < 4; n++) {
      int col = (int)n0 + wc + n * 16 + lr;
      int rowb = (int)m0 + wr + m * 16 + (lane >> 4) * 4;
      #pragma unroll
      for (int r = 0; r < 4; r++) {
        size_t idx = (size_t)(rowb + r) * EE + col;
        gz[idx] = f2bf(bf2f(uz[idx]) * acc[m][n][r]);
      }
    }
  }
}

// ---------------- PV, 256x256 (core8 v3) ----------------
__global__ __launch_bounds__(512, 2) void gpv8_kernel(
    const short* __restrict__ Pg, const short* __restrict__ vTg,
    const short* __restrict__ ug, short* __restrict__ gg)
{
  extern __shared__ __align__(16) short sm[];
  const int b = blockIdx.z;
  const size_t m0 = (size_t)blockIdx.x * 256;
  const size_t n0 = (size_t)blockIdx.y * 256;
  const short* A  = Pg  + (size_t)b * LLL * LLL;
  const short* Bv = vTg + (size_t)b * EE * LLL;
  const int tid = threadIdx.x, w = tid >> 6, l = tid & 63;
  const int lr = l & 15;
  f32x4 acc[8][4];
  core8<LLL, LLL / 64>(A, Bv, m0, n0, tid, sm, acc);
  const short* ub_ = ug + (size_t)b * LLL * EE;
  short* gb_ = gg + (size_t)b * LLL * EE;
  const int rowb0 = (int)m0 + (w >> 2) * 128 + (l >> 4) * 4;
  const int colb0 = (int)n0 + (w & 3) * 64 + lr;
  #pragma unroll
  for (int mf = 0; mf < 8; ++mf) {
    #pragma unroll
    for (int nf = 0; nf < 4; ++nf) {
      int col = colb0 + nf * 16;
      #pragma unroll
      for (int r = 0; r < 4; ++r) {
        size_t idx = (size_t)(rowb0 + mf * 16 + r) * EE + col;
        gb_[idx] = f2bf(bf2f(ub_[idx]) * acc[mf][nf][r]);
      }
    }
  }
}

// ---------------- GEMM2 v2: 256x128 tile, 3-buf rotation, 1 barrier/K-tile ----------------
__global__ __launch_bounds__(512, 1) void gout2_kernel(
    const short* __restrict__ A, const short* __restrict__ Bw,
    const float* __restrict__ b_out, const float* __restrict__ x,
    float* __restrict__ out)
{
  extern __shared__ __align__(16) short sm[];
  const size_t m0 = (size_t)blockIdx.x * 256;
  const size_t n0 = (size_t)blockIdx.y * 128;
  const int tid = threadIdx.x, w = tid >> 6, l = tid & 63;
  const int lr = l & 15;
  const int colsrc = ((l & 7) * 8) ^ ((l >> 3) << 3);
  const short* srcA = A  + (m0 + w * 8 + (l >> 3)) * (size_t)EE + colsrc;
  const short* srcB = Bw + (n0 + w * 8 + (l >> 3)) * (size_t)EE + colsrc;
  const int csw0 = ((l >> 4) * 8) ^ ((l & 7) << 3);
  const int csw1 = (32 + (l >> 4) * 8) ^ ((l & 7) << 3);
  const int mq = w >> 1, nh = w & 1;
  const int ARd = (mq * 64 + lr) * 64;
  const int BRd = 16384 + (nh * 64 + lr) * 64;

  #define GSTA(r_, u_, kt_) gld16(srcA + (u_) * 64 * (size_t)EE + (kt_) * 64, \
                                  &sm[(r_) * 24576 + (u_) * 4096 + w * 512])
  #define GSTB(r_, u_, kt_) gld16(srcB + (u_) * 64 * (size_t)EE + (kt_) * 64, \
                                  &sm[(r_) * 24576 + 16384 + (u_) * 4096 + w * 512])

  f32x4 acc[4][4];
  #pragma unroll
  for (int m = 0; m < 4; m++)
    #pragma unroll
    for (int n = 0; n < 4; n++) acc[m][n] = (f32x4){0.f, 0.f, 0.f, 0.f};

  GSTA(0, 0, 0); GSTA(0, 1, 0); GSTA(0, 2, 0); GSTA(0, 3, 0); GSTB(0, 0, 0); GSTB(0, 1, 0);
  GSTA(1, 0, 1); GSTA(1, 1, 1); GSTA(1, 2, 1); GSTA(1, 3, 1); GSTB(1, 0, 1); GSTB(1, 1, 1);
  VMCNT(6);
  SBAR();
  __builtin_amdgcn_sched_barrier(0);

  const int T = EE / 64;   // 16
  for (int t = 0; t < T; ++t) {
    const int r = t % 3, n2 = (t + 2) % 3;
    const short* Ab = sm + r * 24576 + ARd;
    const short* Bb = sm + r * 24576 + BRd;
    short8 af[4], bf[4];
    if (t + 2 < T) { GSTA(n2, 0, t + 2); GSTA(n2, 1, t + 2); GSTB(n2, 0, t + 2); }
    #pragma unroll
    for (int i = 0; i < 4; ++i) af[i] = *(const short8*)&Ab[i * 1024 + csw0];
    #pragma unroll
    for (int j = 0; j < 4; ++j) bf[j] = *(const short8*)&Bb[j * 1024 + csw0];
    __builtin_amdgcn_s_setprio(1);
    #pragma unroll
    for (int i = 0; i < 4; ++i)
      #pragma unroll
      for (int j = 0; j < 4; ++j)
        MFMA16(af[i], bf[j], acc[i][j]);
    __builtin_amdgcn_s_setprio(0);
    if (t + 2 < T) { GSTA(n2, 2, t + 2); GSTA(n2, 3, t + 2); GSTB(n2, 1, t + 2); }
    #pragma unroll
    for (int i = 0; i < 4; ++i) af[i] = *(const short8*)&Ab[i * 1024 + csw1];
    #pragma unroll
    for (int j = 0; j < 4; ++j) bf[j] = *(const short8*)&Bb[j * 1024 + csw1];
    __builtin_amdgcn_s_setprio(1);
    #pragma unroll
    for (int i = 0; i < 4; ++i)
      #pragma unroll
      for (int j = 0; j < 4; ++j)
        MFMA16(af[i], bf[j], acc[i][j]);
    __builtin_amdgcn_s_setprio(0);
    if (t + 2 < T) { VMCNT(6); } else { VMCNT(0); }
    SBAR();
    __builtin_amdgcn_sched_barrier(0);
  }
  #undef GSTA
  #undef GSTB

  const int rowb0 = (int)m0 + mq * 64 + (l >> 4) * 4;
  const int colb0 = (int)n0 + nh * 64 + lr;
  #pragma unroll
  for (int i = 0; i < 4; ++i) {
    #pragma unroll
    for (int j = 0; j < 4; ++j) {
      int col = colb0 + j * 16;
      float bias = b_out[col];
      #pragma unroll
      for (int r = 0; r < 4; ++r) {
        size_t idx = (size_t)(rowb0 + i * 16 + r) * DIMD + col;
        out[idx] = acc[i][j][r] + bias + x[idx];
      }
    }
  }
}

extern "C" void kernel_launch(void* const* d_in, const int* in_sizes, int n_in,
                              void* d_out, int out_size, void* d_ws, size_t ws_size,
                              hipStream_t stream) {
  const float* x     = (const float*)d_in[0];
  const float* W_uv  = (const float*)d_in[1];
  const float* b_uv  = (const float*)d_in[2];
  const float* gamma = (const float*)d_in[3];
  const float* beta  = (const float*)d_in[4];
  const float* W_out = (const float*)d_in[5];
  const float* b_out = (const float*)d_in[6];
  const float* ln_w  = (const float*)d_in[7];
  const float* ln_b  = (const float*)d_in[8];
  float* out = (float*)d_out;

  char* ws = (char*)d_ws;
  short* W_uvT  = (short*)(ws);
  short* W_outT = (short*)(ws + 2228224);
  short* xn     = (short*)(ws + 3276800);
  short* qb     = (short*)(ws + 20054016);
  short* kb     = (short*)(ws + 24248320);
  short* ub     = (short*)(ws + 28442624);
  short* vTb    = (short*)(ws + 61997056);
  short* gb     = (short*)(ws + 95551488);
  short* Pb     = (short*)(ws + 129105920);

  prepln_kernel<<<dim3(NROW + 400), 256, 0, stream>>>(
      x, ln_w, ln_b, xn, W_uv, W_out, W_uvT, W_outT);
  guv8_kernel<<<dim3(NROW / 256, 9), 512, 131072, stream>>>(
      xn, W_uvT, b_uv, gamma, beta, ub, vTb, qb, kb);

  const long SQ = (long)LLL * SSS;
  const long SP = (long)LLL * LLL;
  const long SV = (long)EE * LLL;
  const long SU = (long)LLL * EE;

  if (ws_size >= 129105920ull + 134217728ull) {
    gqk4_kernel<<<dim3(16, 16, 4), 512, 131072, stream>>>(qb, kb, Pb);
    gpv8_kernel<<<dim3(16, 4, 4), 512, 131072, stream>>>(Pb, vTb, ub, gb);
  } else if (ws_size >= 129105920ull + 33554432ull) {
    for (int b = 0; b < 4; b++) {
      gqk_kernel<<<dim3(32, 32, 1), 256, 0, stream>>>(qb + (size_t)b * SQ, kb + (size_t)b * SQ, Pb, 0, 0, 0);
      gpv_kernel<<<dim3(32, 8, 1), 256, 0, stream>>>(Pb, vTb + (size_t)b * SV, ub + (size_t)b * SU, gb + (size_t)b * SU, 0, 0, 0);
    }
  } else {
    short* Pc = xn;
    for (int b = 0; b < 4; b++) {
      for (int h = 0; h < 2; h++) {
        size_t rowoff = (size_t)b * LLL + (size_t)h * 2048;
        gqk_kernel<<<dim3(16, 32, 1), 256, 0, stream>>>(qb + rowoff * SSS, kb + (size_t)b * SQ, Pc, 0, 0, 0);
        gpv_kernel<<<dim3(16, 8, 1), 256, 0, stream>>>(Pc, vTb + (size_t)b * SV, ub + rowoff * EE, gb + rowoff * EE, 0, 0, 0);
      }
    }
  }

  gout2_kernel<<<dim3(NROW / 256, DIMD / 128), 512, 147456, stream>>>(gb, W_outT, b_out, x, out);
}